// Round 2
// baseline (957.143 us; speedup 1.0000x reference)
//
#include <hip/hip_runtime.h>
#include <math.h>

#define B_  32768
#define K_  1024
#define N_  2048

typedef __bf16 bf16x8 __attribute__((ext_vector_type(8)));
typedef float  f32x4  __attribute__((ext_vector_type(4)));
typedef float  f4     __attribute__((ext_vector_type(4)));
typedef unsigned short us4 __attribute__((ext_vector_type(4)));

__device__ __forceinline__ unsigned short f2bf(float f) {
    unsigned u = __float_as_uint(f);
    u += 0x7fffu + ((u >> 16) & 1u);   // round-to-nearest-even
    return (unsigned short)(u >> 16);
}
__device__ __forceinline__ float bf2f(unsigned short s) {
    return __uint_as_float(((unsigned)s) << 16);
}

// ---------------- pack x || h -> XH bf16 [B, 1024] ----------------
__global__ __launch_bounds__(256) void cvt_xh_kernel(const float* __restrict__ x,
                                                     const float* __restrict__ h,
                                                     unsigned short* __restrict__ XH) {
    unsigned i = (blockIdx.x * 256u + threadIdx.x) * 4u;   // element index in XH
    unsigned col = i & 1023u;
    unsigned row = i >> 10;
    const float* src = (col < 512u) ? (x + (size_t)row * 512u + col)
                                    : (h + (size_t)row * 512u + (col - 512u));
    f4 v = *(const f4*)src;
    us4 o;
    o.x = f2bf(v.x); o.y = f2bf(v.y); o.z = f2bf(v.z); o.w = f2bf(v.w);
    *(us4*)(XH + i) = o;
}

// ---------------- transpose-pack weights -> Wt bf16 [N=2048, K=1024] ----------------
// Wt[n = g*512 + j][k]:  k<512 -> U_g[k][j],  k>=512 -> V_g[k-512][j]
__global__ __launch_bounds__(256) void cvt_w_kernel(
    const float* __restrict__ Uf, const float* __restrict__ Vf,
    const float* __restrict__ Ui, const float* __restrict__ Vi,
    const float* __restrict__ Uo, const float* __restrict__ Vo,
    const float* __restrict__ Uc, const float* __restrict__ Vc,
    unsigned short* __restrict__ Wt) {
    __shared__ float tile[64][65];
    const float* srcs[8] = {Uf, Vf, Ui, Vi, Uo, Vo, Uc, Vc};
    const int w   = blockIdx.z;           // 0..7 : Uf,Vf,Ui,Vi,Uo,Vo,Uc,Vc
    const float* src = srcs[w];
    const int g   = w >> 1;
    const int isV = w & 1;
    const int j0  = blockIdx.x * 64;
    const int k0  = blockIdx.y * 64;
    const int t   = threadIdx.x;
    const int ty  = t >> 6, tx = t & 63;
    #pragma unroll
    for (int r = 0; r < 16; ++r) {
        int kl = ty * 16 + r;
        tile[kl][tx] = src[(size_t)(k0 + kl) * 512 + j0 + tx];   // coalesced over j
    }
    __syncthreads();
    #pragma unroll
    for (int r = 0; r < 16; ++r) {
        int jl = ty * 16 + r;
        Wt[(size_t)(g * 512 + j0 + jl) * 1024 + isV * 512 + k0 + tx] = f2bf(tile[tx][jl]); // coalesced over k
    }
}

// ---------------- GEMM: Pre[B, 2048] = XH @ Wt^T  (bf16 MFMA) ----------------
// 128x128 tile, BK=64, 4 waves of 64x64, 16x16x32 MFMA.
// Register staging (global_load_dwordx4 -> ds_write_b128) with K+1 prefetch:
// global loads for tile it+1 are issued BEFORE the MFMA stage of tile it and
// stay in flight through the MFMAs (per-register vmcnt tracking).
// LDS chunk layout (16B chunks): slot(r,c) = r*8 + (c ^ (r&7)) -> 2-way-only
// bank aliasing on ds_read_b128 fragment reads (free per m136).
__global__ __launch_bounds__(256, 2) void gemm_kernel(const unsigned short* __restrict__ XH,
                                                      const unsigned short* __restrict__ Wt,
                                                      unsigned short* __restrict__ Pre) {
    __shared__ __attribute__((aligned(16))) unsigned short As[128 * 64];
    __shared__ __attribute__((aligned(16))) unsigned short Bs[128 * 64];
    const int t    = threadIdx.x;
    const int lane = t & 63;
    const int w    = t >> 6;
    const int wm   = w >> 1;
    const int wn   = w & 1;
    const int m0   = blockIdx.y * 128;
    const int n0   = blockIdx.x * 128;

    f32x4 acc[4][4];
    #pragma unroll
    for (int i = 0; i < 4; ++i)
        #pragma unroll
        for (int j = 0; j < 4; ++j) { f32x4 z = {0.f, 0.f, 0.f, 0.f}; acc[i][j] = z; }

    // staging geometry (per-thread constant): thread t stages slots L = s*256+t
    size_t gOff[4];     // element offset within the 128xK tile window (add k0 per iter)
    int    lOff[4];     // halfword offset into As/Bs
    #pragma unroll
    for (int s = 0; s < 4; ++s) {
        int L  = s * 256 + t;
        int r  = L >> 3;
        int gc = (L & 7) ^ (r & 7);
        gOff[s] = (size_t)r * K_ + gc * 8;
        lOff[s] = L * 8;                     // slot L at byte L*16
    }
    const unsigned short* xb = XH + (size_t)m0 * K_;
    const unsigned short* wb = Wt + (size_t)n0 * K_;

    uint4 pa[4], pb[4];
    #pragma unroll
    for (int s = 0; s < 4; ++s) {
        pa[s] = *(const uint4*)(xb + gOff[s]);
        pb[s] = *(const uint4*)(wb + gOff[s]);
    }

    for (int it = 0; it < K_ / 64; ++it) {
        __syncthreads();   // all waves done reading LDS from previous iteration
        #pragma unroll
        for (int s = 0; s < 4; ++s) {
            *(uint4*)(As + lOff[s]) = pa[s];   // ds_write_b128 (waits its own vmcnt)
            *(uint4*)(Bs + lOff[s]) = pb[s];
        }
        __syncthreads();   // writes visible to all waves

        if (it + 1 < K_ / 64) {
            const int k1 = (it + 1) * 64;
            #pragma unroll
            for (int s = 0; s < 4; ++s) {
                pa[s] = *(const uint4*)(xb + gOff[s] + k1);   // in flight through MFMAs
                pb[s] = *(const uint4*)(wb + gOff[s] + k1);
            }
        }

        #pragma unroll
        for (int ks = 0; ks < 2; ++ks) {
            bf16x8 af[4], bfr[4];
            const int c = ks * 4 + (lane >> 4);
            #pragma unroll
            for (int mt = 0; mt < 4; ++mt) {
                int r = wm * 64 + mt * 16 + (lane & 15);
                int slot = r * 8 + (c ^ (r & 7));
                af[mt] = *(const bf16x8*)(As + slot * 8);
            }
            #pragma unroll
            for (int nt = 0; nt < 4; ++nt) {
                int r = wn * 64 + nt * 16 + (lane & 15);
                int slot = r * 8 + (c ^ (r & 7));
                bfr[nt] = *(const bf16x8*)(Bs + slot * 8);
            }
            #pragma unroll
            for (int mt = 0; mt < 4; ++mt)
                #pragma unroll
                for (int nt = 0; nt < 4; ++nt)
                    acc[mt][nt] = __builtin_amdgcn_mfma_f32_16x16x32_bf16(af[mt], bfr[nt], acc[mt][nt], 0, 0, 0);
        }
    }

    // epilogue: C/D layout col = lane&15, row = (lane>>4)*4 + reg
    const int colb = n0 + wn * 64 + (lane & 15);
    const int rowb = m0 + wm * 64 + (lane >> 4) * 4;
    #pragma unroll
    for (int mt = 0; mt < 4; ++mt)
        #pragma unroll
        for (int nt = 0; nt < 4; ++nt) {
            const int col = colb + nt * 16;
            const int rw  = rowb + mt * 16;
            #pragma unroll
            for (int rr = 0; rr < 4; ++rr)
                Pre[(size_t)(rw + rr) * N_ + col] = f2bf(acc[mt][nt][rr]);
        }
}

// ---------------- elementwise gates + fused logits/softmax ----------------
__global__ __launch_bounds__(256) void ew_kernel(const unsigned short* __restrict__ Pre,
                                                 const float* __restrict__ cell,
                                                 const float* __restrict__ bfp, const float* __restrict__ bip,
                                                 const float* __restrict__ bop, const float* __restrict__ bcp,
                                                 const float* __restrict__ Wout, const float* __restrict__ bout,
                                                 float* __restrict__ out) {
    const int row = blockIdx.x;
    const int t   = threadIdx.x;
    const unsigned short* pr = Pre + (size_t)row * N_;
    float p0 = 0.f, p1 = 0.f;
    #pragma unroll
    for (int jj = 0; jj < 2; ++jj) {
        const int j = t + jj * 256;
        float gf = 1.f / (1.f + __expf(-(bf2f(pr[j])        + bfp[j])));
        float gi = 1.f / (1.f + __expf(-(bf2f(pr[512 + j])  + bip[j])));
        float go = 1.f / (1.f + __expf(-(bf2f(pr[1024 + j]) + bop[j])));
        float ch = tanhf(bf2f(pr[1536 + j]) + bcp[j]);
        float cold = cell[(size_t)row * 512 + j];
        float cn = gf * cold + gi * ch;
        float hn = go * tanhf(cn);
        out[65536 + (size_t)row * 512 + j]            = hn;
        out[65536 + 16777216 + (size_t)row * 512 + j] = cn;
        p0 += hn * Wout[j * 2 + 0];
        p1 += hn * Wout[j * 2 + 1];
    }
    #pragma unroll
    for (int off = 32; off > 0; off >>= 1) {
        p0 += __shfl_down(p0, off);
        p1 += __shfl_down(p1, off);
    }
    __shared__ float r0[4], r1[4];
    if ((t & 63) == 0) { r0[t >> 6] = p0; r1[t >> 6] = p1; }
    __syncthreads();
    if (t == 0) {
        float l0 = r0[0] + r0[1] + r0[2] + r0[3] + bout[0];
        float l1 = r1[0] + r1[1] + r1[2] + r1[3] + bout[1];
        float mx = fmaxf(l0, l1);
        float e0 = __expf(l0 - mx), e1 = __expf(l1 - mx);
        float s  = e0 + e1;
        out[(size_t)row * 2 + 0] = e0 / s;
        out[(size_t)row * 2 + 1] = e1 / s;
    }
}

// ---------------- fallback (only if workspace is too small): naive fp32 ----------------
__global__ __launch_bounds__(256) void fallback_kernel(
    const float* __restrict__ x, const float* __restrict__ h, const float* __restrict__ cell,
    const float* __restrict__ Uf, const float* __restrict__ Vf, const float* __restrict__ bfp,
    const float* __restrict__ Ui, const float* __restrict__ Vi, const float* __restrict__ bip,
    const float* __restrict__ Uo, const float* __restrict__ Vo, const float* __restrict__ bop,
    const float* __restrict__ Uc, const float* __restrict__ Vc, const float* __restrict__ bcp,
    const float* __restrict__ Wout, const float* __restrict__ bout, float* __restrict__ out) {
    const int row = blockIdx.x;
    const int t   = threadIdx.x;
    __shared__ float xs[512], hs[512];
    xs[t]       = x[(size_t)row * 512 + t];
    xs[t + 256] = x[(size_t)row * 512 + t + 256];
    hs[t]       = h[(size_t)row * 512 + t];
    hs[t + 256] = h[(size_t)row * 512 + t + 256];
    __syncthreads();
    float p0 = 0.f, p1 = 0.f;
    for (int jj = 0; jj < 2; ++jj) {
        const int j = t + jj * 256;
        float af = bfp[j], ai = bip[j], ao = bop[j], ac = bcp[j];
        for (int k = 0; k < 512; ++k) {
            float xv = xs[k], hv = hs[k];
            af += xv * Uf[k * 512 + j] + hv * Vf[k * 512 + j];
            ai += xv * Ui[k * 512 + j] + hv * Vi[k * 512 + j];
            ao += xv * Uo[k * 512 + j] + hv * Vo[k * 512 + j];
            ac += xv * Uc[k * 512 + j] + hv * Vc[k * 512 + j];
        }
        float gf = 1.f / (1.f + __expf(-af));
        float gi = 1.f / (1.f + __expf(-ai));
        float go = 1.f / (1.f + __expf(-ao));
        float ch = tanhf(ac);
        float cold = cell[(size_t)row * 512 + j];
        float cn = gf * cold + gi * ch;
        float hn = go * tanhf(cn);
        out[65536 + (size_t)row * 512 + j]            = hn;
        out[65536 + 16777216 + (size_t)row * 512 + j] = cn;
        p0 += hn * Wout[j * 2 + 0];
        p1 += hn * Wout[j * 2 + 1];
    }
    #pragma unroll
    for (int off = 32; off > 0; off >>= 1) {
        p0 += __shfl_down(p0, off);
        p1 += __shfl_down(p1, off);
    }
    __shared__ float r0[4], r1[4];
    if ((t & 63) == 0) { r0[t >> 6] = p0; r1[t >> 6] = p1; }
    __syncthreads();
    if (t == 0) {
        float l0 = r0[0] + r0[1] + r0[2] + r0[3] + bout[0];
        float l1 = r1[0] + r1[1] + r1[2] + r1[3] + bout[1];
        float mx = fmaxf(l0, l1);
        float e0 = __expf(l0 - mx), e1 = __expf(l1 - mx);
        float s  = e0 + e1;
        out[(size_t)row * 2 + 0] = e0 / s;
        out[(size_t)row * 2 + 1] = e1 / s;
    }
}

extern "C" void kernel_launch(void* const* d_in, const int* in_sizes, int n_in,
                              void* d_out, int out_size, void* d_ws, size_t ws_size,
                              hipStream_t stream) {
    const float* x    = (const float*)d_in[0];
    const float* h    = (const float*)d_in[1];
    const float* c    = (const float*)d_in[2];
    const float* Uf   = (const float*)d_in[3];
    const float* Vf   = (const float*)d_in[4];
    const float* bfp  = (const float*)d_in[5];
    const float* Ui   = (const float*)d_in[6];
    const float* Vi   = (const float*)d_in[7];
    const float* bip  = (const float*)d_in[8];
    const float* Uo   = (const float*)d_in[9];
    const float* Vo   = (const float*)d_in[10];
    const float* bop  = (const float*)d_in[11];
    const float* Uc   = (const float*)d_in[12];
    const float* Vc   = (const float*)d_in[13];
    const float* bcp  = (const float*)d_in[14];
    const float* Wout = (const float*)d_in[15];
    const float* bout = (const float*)d_in[16];
    float* out = (float*)d_out;

    const size_t needXH  = (size_t)B_ * K_ * 2;   // 64 MB
    const size_t needWt  = (size_t)N_ * K_ * 2;   //  4 MB
    const size_t needPre = (size_t)B_ * N_ * 2;   // 128 MB

    if (ws_size >= needXH + needWt + needPre) {
        unsigned short* XH  = (unsigned short*)d_ws;
        unsigned short* Wt  = (unsigned short*)((char*)d_ws + needXH);
        unsigned short* Pre = (unsigned short*)((char*)d_ws + needXH + needWt);

        cvt_xh_kernel<<<(B_ * K_) / (256 * 4), 256, 0, stream>>>(x, h, XH);
        cvt_w_kernel<<<dim3(8, 8, 8), 256, 0, stream>>>(Uf, Vf, Ui, Vi, Uo, Vo, Uc, Vc, Wt);
        gemm_kernel<<<dim3(N_ / 128, B_ / 128), 256, 0, stream>>>(XH, Wt, Pre);
        ew_kernel<<<B_, 256, 0, stream>>>(Pre, c, bfp, bip, bop, bcp, Wout, bout, out);
    } else {
        fallback_kernel<<<B_, 256, 0, stream>>>(x, h, c, Uf, Vf, bfp, Ui, Vi, bip,
                                                Uo, Vo, bop, Uc, Vc, bcp, Wout, bout, out);
    }
}